// Round 8
// baseline (998.447 us; speedup 1.0000x reference)
//
#include <hip/hip_runtime.h>
#include <stdint.h>

typedef unsigned long long u64;
typedef unsigned int u32;

#define NVERT 300000
#define NTET  1200000
#define NE    (NTET*6)              // 7,200,000 edges
#define TILE  4096
#define NTILES ((NE + TILE - 1)/TILE)   // 1758
#define IDXBITS 23
#define IDXMASK ((1u<<IDXBITS)-1)
#define CODESHIFT 24                // key = code<<24 | cross<<23 | idx
#define RBITS 10
#define RBINS 1024
#define SORT_BASE 24                // sort code bits only (bits 24..63)

// mapping-scatter buckets
#define BSHIFT 16
#define BSZ    65536
#define NBUCK  110
#define BPB    8
#define STAGECAP 2240               // crossing-only stage capacity (mean 2048 + 6 sigma)

// output layout (float32 elements)
#define VERTS_OFF 0
#define FACES_OFF 21600000
#define NUMT_OFF  28800000
#define CROSS_OFF 30000000

__constant__ int c_ea[6] = {0,0,0,1,1,2};
__constant__ int c_eb[6] = {1,2,3,2,3,3};
__constant__ int c_numtri[16] = {0,1,1,2,1,2,2,1,1,2,2,1,2,1,1,0};
__constant__ int c_tritab[16][6] = {
 {-1,-1,-1,-1,-1,-1},{1,0,2,-1,-1,-1},{4,0,3,-1,-1,-1},{1,4,2,1,3,4},
 {3,1,5,-1,-1,-1},{2,3,0,2,5,3},{1,4,0,1,5,4},{4,2,5,-1,-1,-1},
 {4,5,2,-1,-1,-1},{4,1,0,4,5,1},{3,2,0,3,5,2},{1,3,5,-1,-1,-1},
 {4,1,2,4,3,1},{3,0,4,-1,-1,-1},{2,0,1,-1,-1,-1},{-1,-1,-1,-1,-1,-1}};

__device__ __forceinline__ int sw(int j){ return j ^ ((j >> 4) & 15); }

// one thread per TET: 6 keys (cross bit embedded) + occ nibble into NUMT region
__global__ void k_pack(const int* __restrict__ tet, const float* __restrict__ sdf,
                       u64* __restrict__ dst, float* __restrict__ occF){
  int t = blockIdx.x*blockDim.x + threadIdx.x;
  if (t >= NTET) return;
  int4 q = ((const int4*)tet)[t];
  int v[4] = {q.x, q.y, q.z, q.w};
  u32 o[4];
  int occ = 0;
  #pragma unroll
  for (int j=0;j<4;j++){ o[j] = sdf[v[j]] > 0.f ? 1u : 0u; occ |= (int)o[j] << j; }
  occF[t] = (float)occ;
  u64 base = (u64)t*6;
  #pragma unroll
  for (int k=0;k<6;k++){
    int a = v[c_ea[k]], b = v[c_eb[k]];
    u64 cross = (o[c_ea[k]] != o[c_eb[k]]) ? 1ull : 0ull;
    int e0 = min(a,b), e1 = max(a,b);
    u64 code = (u64)e0 * NVERT + (u64)e1;
    dst[base+k] = (code << CODESHIFT) | (cross << IDXBITS) | (base + (u64)k);
  }
}

__global__ void k_psd(const float* __restrict__ pos, const float* __restrict__ sdf,
                      float4* __restrict__ psd){
  int v = blockIdx.x*blockDim.x + threadIdx.x;
  if (v < NVERT) psd[v] = make_float4(pos[3*v], pos[3*v+1], pos[3*v+2], sdf[v]);
}

__global__ void k_fillm1(float4* __restrict__ p, int n4){
  int i = blockIdx.x*blockDim.x + threadIdx.x;
  if (i < n4) p[i] = make_float4(-1.f,-1.f,-1.f,-1.f);
}

__global__ __launch_bounds__(256) void k_hist(const u64* __restrict__ src, u32* __restrict__ hist, int shift){
  __shared__ u32 h[RBINS];
  int tid = threadIdx.x;
  #pragma unroll
  for (int r=0;r<RBINS/256;r++) h[tid + r*256] = 0;
  __syncthreads();
  int base = blockIdx.x * TILE;
  for (int k=0;k<16;k++){
    int i = base + k*256 + tid;
    if (i < NE) atomicAdd(&h[(u32)((src[i] >> shift) & (RBINS-1))], 1u);
  }
  __syncthreads();
  #pragma unroll
  for (int r=0;r<RBINS/256;r++){
    int d = tid + r*256;
    hist[(size_t)d * NTILES + blockIdx.x] = h[d];
  }
}

// per-digit exclusive scan across tiles (in place), digit totals out; grid = RBINS
__global__ void k_scan_digit(u32* __restrict__ hist, u32* __restrict__ digitTot){
  __shared__ u32 s[256];
  int d = blockIdx.x, tid = threadIdx.x;
  u32* row = hist + (size_t)d * NTILES;
  u32 carry = 0;
  for (int start=0; start<NTILES; start+=256){
    int idx = start + tid;
    u32 x = (idx < NTILES) ? row[idx] : 0;
    s[tid] = x; __syncthreads();
    for (int off=1; off<256; off<<=1){
      u32 t = (tid >= off) ? s[tid-off] : 0;
      __syncthreads();
      s[tid] += t;
      __syncthreads();
    }
    u32 incl = s[tid];
    u32 tot  = s[255];
    if (idx < NTILES) row[idx] = carry + incl - x;
    carry += tot;
    __syncthreads();
  }
  if (tid==0) digitTot[d] = carry;
}

__global__ __launch_bounds__(1024) void k_scan_base(const u32* __restrict__ digitTot, u32* __restrict__ digitOff){
  __shared__ u32 s[RBINS];
  int tid = threadIdx.x;
  u32 x = digitTot[tid];
  s[tid]=x; __syncthreads();
  for (int off=1; off<RBINS; off<<=1){
    u32 t=(tid>=off)?s[tid-off]:0;
    __syncthreads();
    s[tid]+=t;
    __syncthreads();
  }
  digitOff[tid] = s[tid]-x;
}

// 5 rounds of 2-bit stable splits (packed 4x16-bit counters in one u64 scan)
__global__ __launch_bounds__(256) void k_scatter(const u64* __restrict__ src, u64* __restrict__ dst,
      const u32* __restrict__ hist, const u32* __restrict__ digitOff, int shift){
  __shared__ u64 keys[TILE];
  __shared__ u64 sc[256];
  __shared__ u32 lstart[RBINS];
  int tid = threadIdx.x;
  int base = blockIdx.x * TILE;
  for (int k=0;k<16;k++){
    int j = k*256 + tid;
    int i = base + j;
    keys[sw(j)] = (i < NE) ? src[i] : ~0ull;
  }
  __syncthreads();
  for (int q=0;q<RBITS;q+=2){
    int sh = shift + q;
    u64 myk[16];
    u32 vpack = 0;
    u64 cnt = 0;
    #pragma unroll
    for (int k=0;k<16;k++){
      myk[k] = keys[sw(tid*16+k)];
      u32 v = (u32)((myk[k] >> sh) & 3);
      vpack |= v << (2*k);
      cnt += 1ull << (16*v);
    }
    sc[tid] = cnt; __syncthreads();
    for (int off=1; off<256; off<<=1){
      u64 t=(tid>=off)?sc[tid-off]:0;
      __syncthreads();
      sc[tid]+=t;
      __syncthreads();
    }
    u64 incl = sc[tid];
    u64 tot  = sc[255];
    __syncthreads();
    u64 run = incl - cnt;   // packed exclusive counts (elements in earlier threads)
    u32 T0=(u32)(tot&0xFFFF), T1=(u32)((tot>>16)&0xFFFF), T2=(u32)((tot>>32)&0xFFFF);
    u64 Bp = ((u64)(T0) << 16) | ((u64)(T0+T1) << 32) | ((u64)(T0+T1+T2) << 48);
    #pragma unroll
    for (int k=0;k<16;k++){
      u32 v = (vpack >> (2*k)) & 3;
      u32 pos = (u32)((Bp >> (16*v)) & 0xFFFF) + (u32)((run >> (16*v)) & 0xFFFF);
      run += 1ull << (16*v);
      keys[sw((int)pos)] = myk[k];
    }
    __syncthreads();
  }
  for (int k=0;k<16;k++){
    int j = k*256+tid;
    u32 d = (u32)((keys[sw(j)] >> shift) & (RBINS-1));
    bool headj = (j==0) || (((keys[sw(j-1)] >> shift) & (RBINS-1)) != d);
    if (headj) lstart[d] = (u32)j;
  }
  __syncthreads();
  for (int k=0;k<16;k++){
    int j = k*256+tid;
    u64 key = keys[sw(j)];
    if (key == ~0ull) continue;
    u32 d = (u32)((key >> shift) & (RBINS-1));
    u32 gpos = digitOff[d] + hist[(size_t)d*NTILES + blockIdx.x] + (u32)j - lstart[d];
    dst[gpos] = key;
  }
}

// streaming per-tile (head, crossHead) counts — no gathers (cross from key bit)
__global__ __launch_bounds__(256) void k_tilesum(const u64* __restrict__ A, u64* __restrict__ tileSums){
  __shared__ u64 s[256];
  int tid = threadIdx.x;
  int start = blockIdx.x*TILE + tid*16;
  u64 prev = (start > 0 && start <= NE) ? A[start-1] : ~0ull;
  u32 th=0, tc=0;
  #pragma unroll
  for (int k=0;k<16;k++){
    int i = start + k;
    if (i < NE){
      u64 v = A[i];
      if ((v>>CODESHIFT) != (prev>>CODESHIFT)){
        th++;
        if ((v>>IDXBITS) & 1ull) tc++;
      }
      prev = v;
    }
  }
  s[tid] = ((u64)th<<32) | (u64)tc;
  __syncthreads();
  for (int off=128; off>0; off>>=1){
    if (tid<off) s[tid]+=s[tid+off];
    __syncthreads();
  }
  if (tid==0) tileSums[blockIdx.x] = s[0];
}

__global__ void k_scan_tiles(u64* __restrict__ tileSums, u64* __restrict__ tileOff){
  __shared__ u64 s[256];
  int tid = threadIdx.x;
  u64 carry=0;
  for (int start=0; start<NTILES; start+=256){
    int idx=start+tid;
    u64 x = (idx<NTILES)? tileSums[idx] : 0;
    s[tid]=x; __syncthreads();
    for (int off=1;off<256;off<<=1){
      u64 t=(tid>=off)?s[tid-off]:0;
      __syncthreads();
      s[tid]+=t;
      __syncthreads();
    }
    u64 incl=s[tid], tot=s[255];
    if (idx<NTILES) tileOff[idx] = carry + incl - x;
    carry += tot;
    __syncthreads();
  }
}

// fused post-sort pass with precomputed tile offsets (no lookback, no polling)
// + LDS-staged crossing-only pairs (capped; per-tile fallback to direct writes)
__global__ __launch_bounds__(256) void k_emit_all(const u64* __restrict__ A,
     const float4* __restrict__ psd, const u64* __restrict__ tileOff,
     u64* __restrict__ pairs, u32* __restrict__ cursors,
     float* __restrict__ verts, float* __restrict__ crossing_out){
  __shared__ u64 s[256];
  __shared__ u32 cnt[NBUCK], lcur[NBUCK];
  __shared__ u32 lofs[NBUCK+1];
  __shared__ u32 gbase[NBUCK];
  __shared__ u32 pscan[128];
  __shared__ u64 stage[STAGECAP];
  int tid=threadIdx.x, blk=blockIdx.x;
  int start = blk*TILE + tid*16;
  if (tid < NBUCK){ cnt[tid]=0; lcur[tid]=0; }
  u64 prev = (start > 0 && start <= NE) ? A[start-1] : ~0ull;
  u64 myk[16];
  u32 headm=0, crossm=0;
  #pragma unroll
  for (int k=0;k<16;k++){
    int i = start + k;
    u64 v = 0;
    if (i<NE){
      v = A[i];
      if ((v>>CODESHIFT) != (prev>>CODESHIFT)) headm |= 1u<<k;
      if ((v>>IDXBITS) & 1ull) crossm |= 1u<<k;
      prev = v;
    }
    myk[k]=v;
  }
  __syncthreads();
  // crossing-only bucket counts
  #pragma unroll
  for (int k=0;k<16;k++){
    if ((start+k) < NE && ((crossm>>k)&1u))
      atomicAdd(&cnt[((u32)myk[k] & IDXMASK)>>BSHIFT], 1u);
  }
  u32 th = __popc(headm), tc = __popc(headm & crossm);
  u64 x = ((u64)th<<32)|(u64)tc;
  s[tid]=x; __syncthreads();
  for (int off=1;off<256;off<<=1){
    u64 t=(tid>=off)?s[tid-off]:0;
    __syncthreads();
    s[tid]+=t;
    __syncthreads();
  }
  u64 excl = s[tid]-x;
  // bucket prefix over NBUCK (inclusive scan in pscan)
  if (tid < 128) pscan[tid] = (tid < NBUCK) ? cnt[tid] : 0;
  __syncthreads();
  for (int off=1; off<128; off<<=1){
    u32 t = 0;
    if (tid < 128 && tid >= off) t = pscan[tid-off];
    __syncthreads();
    if (tid < 128) pscan[tid] += t;
    __syncthreads();
  }
  if (tid < NBUCK) lofs[tid] = pscan[tid] - cnt[tid];
  if (tid == 0) lofs[NBUCK] = pscan[127];
  if (tid < NBUCK) gbase[tid] = atomicAdd(&cursors[tid], cnt[tid]);
  __syncthreads();
  bool use_stage = (lofs[NBUCK] <= STAGECAP);
  u64 baseOff = tileOff[blk] + excl;
  u32 H = (u32)(baseOff>>32);
  u32 C = (u32)(baseOff & 0xFFFFFFFFull);
  #pragma unroll
  for (int k=0;k<16;k++){
    int i = start+k;
    if (i>=NE) break;
    bool head  = (headm>>k)&1u;
    bool cross = (crossm>>k)&1u;
    if (head){ H++; if(cross) C++; }
    if (cross){
      int m = (int)C-1;
      u32 orig = (u32)myk[k] & IDXMASK;
      u32 b = orig>>BSHIFT;
      u32 r = atomicAdd(&lcur[b], 1u);
      u64 pr = ((u64)orig<<32) | (u64)(u32)m;
      if (use_stage) stage[lofs[b] + r] = pr;
      else           pairs[(size_t)b*BSZ + gbase[b] + r] = pr;
    }
    if (head){
      crossing_out[H-1] = cross ? 1.f : 0.f;
      if (cross){
        int m = (int)C-1;
        u64 code = myk[k]>>CODESHIFT;
        u32 u0=(u32)(code/NVERT), u1=(u32)(code%NVERT);
        float4 a = psd[u0], bb = psd[u1];
        float denom = a.w - bb.w;
        float w0 = (-bb.w)/denom, w1 = a.w/denom;
        verts[3*m+0] = a.x*w0 + bb.x*w1;
        verts[3*m+1] = a.y*w0 + bb.y*w1;
        verts[3*m+2] = a.z*w0 + bb.z*w1;
      }
    }
  }
  __syncthreads();
  if (use_stage){
    // burst copy-out: contiguous run per bucket
    int ncross = (int)lofs[NBUCK];
    for (int j = tid; j < ncross; j += 256){
      int lo=0, hi=NBUCK;
      while (hi - lo > 1){ int mid=(lo+hi)>>1; if ((int)lofs[mid] <= j) lo=mid; else hi=mid; }
      pairs[(size_t)lo*BSZ + gbase[lo] + (u32)(j - (int)lofs[lo])] = stage[j];
    }
  }
}

// per-bucket scatter of mapping into L2-resident 256KB window; count from cursors
__global__ void k_map_scatter(const u64* __restrict__ pairs, const u32* __restrict__ cursors,
                              float* __restrict__ mapF){
  int b = blockIdx.x / BPB, sub = blockIdx.x % BPB;
  u32 n = cursors[b];
  const u64* p = pairs + (size_t)b*BSZ;
  for (u32 i = (u32)(sub*256 + threadIdx.x); i < n; i += BPB*256){
    u64 v = p[i];
    mapF[(u32)(v>>32)] = (float)(int)(u32)v;
  }
}

// occF (== numt region) read, then overwritten per-element by the same thread
__global__ void k_faces(const float* __restrict__ occF, float* faceRegion, float* __restrict__ numt){
  int t = blockIdx.x*blockDim.x + threadIdx.x;
  if (t>=NTET) return;
  int occ = (int)occF[t];
  int ntri = c_numtri[occ];
  float em[6];
  #pragma unroll
  for (int j=0;j<6;j++) em[j] = faceRegion[t*6+j];
  float f[6];
  #pragma unroll
  for (int j=0;j<6;j++){
    int tri = c_tritab[occ][j];
    f[j] = ((j/3) < ntri) ? em[tri] : -1.f;
  }
  #pragma unroll
  for (int j=0;j<6;j++) faceRegion[t*6+j] = f[j];
  numt[t] = (float)ntri;
}

extern "C" void kernel_launch(void* const* d_in, const int* in_sizes, int n_in,
                              void* d_out, int out_size, void* d_ws, size_t ws_size,
                              hipStream_t stream) {
  const float* pos = (const float*)d_in[0];
  const float* sdf = (const float*)d_in[1];
  const int*   tet = (const int*)d_in[2];
  float* out = (float*)d_out;

  // ws layout (hist aliases pairs region: disjoint lifetimes)
  char* w = (char*)d_ws;
  u64* bufA     = (u64*)w;                         // 57,600,000
  u32* digitTot = (u32*)(w + 57600000);            // 4096
  u32* digitOff = (u32*)(w + 57604096);            // 4096
  u64* tileSums = (u64*)(w + 57608192);            // 14,064
  u64* tileOff  = (u64*)(w + 57622256);            // 14,064
  u32* cursors  = (u32*)(w + 57636320);            // 448
  float4* psd   = (float4*)(w + 57636768);         // 4,800,000
  u64* pairs_ws = (u64*)(w + 62436768);            // 57,600,000 -> ends 120,036,768
  u32* hist     = (u32*)pairs_ws;                  // 7,200,768 (used only during sort)

  u64* bufB = (u64*)d_out;   // first 57.6MB of d_out as sort pong buffer

  k_pack<<<(NTET+255)/256, 256, 0, stream>>>(tet, sdf, bufA, out + NUMT_OFF);
  k_psd<<<(NVERT+255)/256, 256, 0, stream>>>(pos, sdf, psd);
  // faces region default -1.0f (non-crossing mapping); bytes 86.4MB..115.2MB of d_out — no overlap with bufB
  k_fillm1<<<(7200000/4 + 255)/256, 256, 0, stream>>>((float4*)(out + FACES_OFF), 7200000/4);

  u64 *src = bufA, *dst = bufB;
  for (int p=0; p<4; p++){
    int shift = SORT_BASE + RBITS*p;
    k_hist<<<NTILES, 256, 0, stream>>>(src, hist, shift);
    k_scan_digit<<<RBINS, 256, 0, stream>>>(hist, digitTot);
    k_scan_base<<<1, 1024, 0, stream>>>(digitTot, digitOff);
    k_scatter<<<NTILES, 256, 0, stream>>>(src, dst, hist, digitOff, shift);
    u64* tmp = src; src = dst; dst = tmp;
  }
  // 4 passes: bufA->bufB->bufA->bufB->bufA — sorted array in bufA (ws)

  k_tilesum<<<NTILES, 256, 0, stream>>>(bufA, tileSums);
  k_scan_tiles<<<1, 256, 0, stream>>>(tileSums, tileOff);

  hipMemsetAsync(out + VERTS_OFF, 0, (size_t)21600000*4, stream);
  hipMemsetAsync(out + CROSS_OFF, 0, (size_t)7200000*4, stream);
  hipMemsetAsync(cursors, 0, NBUCK*sizeof(u32), stream);

  k_emit_all<<<NTILES, 256, 0, stream>>>(bufA, psd, tileOff, pairs_ws, cursors,
                                         out + VERTS_OFF, out + CROSS_OFF);
  k_map_scatter<<<NBUCK*BPB, 256, 0, stream>>>(pairs_ws, cursors, out + FACES_OFF);
  k_faces<<<(NTET+255)/256, 256, 0, stream>>>(out + NUMT_OFF, out + FACES_OFF, out + NUMT_OFF);
}

// Round 9
// 865.875 us; speedup vs baseline: 1.1531x; 1.1531x over previous
//
#include <hip/hip_runtime.h>
#include <stdint.h>

typedef unsigned long long u64;
typedef unsigned int u32;

#define NVERT 300000
#define NTET  1200000
#define NE    (NTET*6)              // 7,200,000 edges
#define TILE  4096
#define NTILES ((NE + TILE - 1)/TILE)   // 1758
#define IDXBITS 23
#define IDXMASK ((1u<<IDXBITS)-1)
#define CODESHIFT 24                // key = code<<24 | cross<<23 | idx
#define RBITS 10
#define RBINS 1024
#define SORT_BASE 24

// mapping-scatter buckets
#define BSHIFT 16
#define BSZ    65536
#define NBUCK  110
#define BPB    8
#define STAGECAP 2240

// output layout (float32 elements)
#define VERTS_OFF 0
#define FACES_OFF 21600000
#define NUMT_OFF  28800000
#define CROSS_OFF 30000000
#define CODES_ELEM 14000000         // codes array at bytes 56MB..86.4MB of d_out (capacity 3.8M u64)

__constant__ int c_ea[6] = {0,0,0,1,1,2};
__constant__ int c_eb[6] = {1,2,3,2,3,3};
__constant__ int c_numtri[16] = {0,1,1,2,1,2,2,1,1,2,2,1,2,1,1,0};
__constant__ int c_tritab[16][6] = {
 {-1,-1,-1,-1,-1,-1},{1,0,2,-1,-1,-1},{4,0,3,-1,-1,-1},{1,4,2,1,3,4},
 {3,1,5,-1,-1,-1},{2,3,0,2,5,3},{1,4,0,1,5,4},{4,2,5,-1,-1,-1},
 {4,5,2,-1,-1,-1},{4,1,0,4,5,1},{3,2,0,3,5,2},{1,3,5,-1,-1,-1},
 {4,1,2,4,3,1},{3,0,4,-1,-1,-1},{2,0,1,-1,-1,-1},{-1,-1,-1,-1,-1,-1}};

__device__ __forceinline__ int sw(int j){ return j ^ ((j >> 4) & 15); }

__global__ void k_pack(const int* __restrict__ tet, const float* __restrict__ sdf,
                       u64* __restrict__ dst, float* __restrict__ occF){
  int t = blockIdx.x*blockDim.x + threadIdx.x;
  if (t >= NTET) return;
  int4 q = ((const int4*)tet)[t];
  int v[4] = {q.x, q.y, q.z, q.w};
  u32 o[4];
  int occ = 0;
  #pragma unroll
  for (int j=0;j<4;j++){ o[j] = sdf[v[j]] > 0.f ? 1u : 0u; occ |= (int)o[j] << j; }
  occF[t] = (float)occ;
  u64 base = (u64)t*6;
  #pragma unroll
  for (int k=0;k<6;k++){
    int a = v[c_ea[k]], b = v[c_eb[k]];
    u64 cross = (o[c_ea[k]] != o[c_eb[k]]) ? 1ull : 0ull;
    int e0 = min(a,b), e1 = max(a,b);
    u64 code = (u64)e0 * NVERT + (u64)e1;
    dst[base+k] = (code << CODESHIFT) | (cross << IDXBITS) | (base + (u64)k);
  }
}

__global__ void k_psd(const float* __restrict__ pos, const float* __restrict__ sdf,
                      float4* __restrict__ psd){
  int v = blockIdx.x*blockDim.x + threadIdx.x;
  if (v < NVERT) psd[v] = make_float4(pos[3*v], pos[3*v+1], pos[3*v+2], sdf[v]);
}

__global__ void k_fillm1(float4* __restrict__ p, int n4){
  int i = blockIdx.x*blockDim.x + threadIdx.x;
  if (i < n4) p[i] = make_float4(-1.f,-1.f,-1.f,-1.f);
}

__global__ __launch_bounds__(256) void k_hist(const u64* __restrict__ src, u32* __restrict__ hist, int shift){
  __shared__ u32 h[RBINS];
  int tid = threadIdx.x;
  #pragma unroll
  for (int r=0;r<RBINS/256;r++) h[tid + r*256] = 0;
  __syncthreads();
  int base = blockIdx.x * TILE;
  for (int k=0;k<16;k++){
    int i = base + k*256 + tid;
    if (i < NE) atomicAdd(&h[(u32)((src[i] >> shift) & (RBINS-1))], 1u);
  }
  __syncthreads();
  #pragma unroll
  for (int r=0;r<RBINS/256;r++){
    int d = tid + r*256;
    hist[(size_t)d * NTILES + blockIdx.x] = h[d];
  }
}

__global__ void k_scan_digit(u32* __restrict__ hist, u32* __restrict__ digitTot){
  __shared__ u32 s[256];
  int d = blockIdx.x, tid = threadIdx.x;
  u32* row = hist + (size_t)d * NTILES;
  u32 carry = 0;
  for (int start=0; start<NTILES; start+=256){
    int idx = start + tid;
    u32 x = (idx < NTILES) ? row[idx] : 0;
    s[tid] = x; __syncthreads();
    for (int off=1; off<256; off<<=1){
      u32 t = (tid >= off) ? s[tid-off] : 0;
      __syncthreads();
      s[tid] += t;
      __syncthreads();
    }
    u32 incl = s[tid];
    u32 tot  = s[255];
    if (idx < NTILES) row[idx] = carry + incl - x;
    carry += tot;
    __syncthreads();
  }
  if (tid==0) digitTot[d] = carry;
}

__global__ __launch_bounds__(1024) void k_scan_base(const u32* __restrict__ digitTot, u32* __restrict__ digitOff){
  __shared__ u32 s[RBINS];
  int tid = threadIdx.x;
  u32 x = digitTot[tid];
  s[tid]=x; __syncthreads();
  for (int off=1; off<RBINS; off<<=1){
    u32 t=(tid>=off)?s[tid-off]:0;
    __syncthreads();
    s[tid]+=t;
    __syncthreads();
  }
  digitOff[tid] = s[tid]-x;
}

// 5 rounds of 2-bit stable splits; wave64 shuffle scan (2 barriers/round)
__global__ __launch_bounds__(256) void k_scatter(const u64* __restrict__ src, u64* __restrict__ dst,
      const u32* __restrict__ hist, const u32* __restrict__ digitOff, int shift){
  __shared__ u64 keys[TILE];
  __shared__ u64 wsum[4];
  __shared__ u32 lstart[RBINS];
  int tid = threadIdx.x;
  int base = blockIdx.x * TILE;
  for (int k=0;k<16;k++){
    int j = k*256 + tid;
    int i = base + j;
    keys[sw(j)] = (i < NE) ? src[i] : ~0ull;
  }
  __syncthreads();
  for (int q=0;q<RBITS;q+=2){
    int sh = shift + q;
    u64 myk[16];
    u32 vpack = 0;
    u64 cnt = 0;
    #pragma unroll
    for (int k=0;k<16;k++){
      myk[k] = keys[sw(tid*16+k)];
      u32 d2 = (u32)((myk[k] >> sh) & 3);
      vpack |= d2 << (2*k);
      cnt += 1ull << (16*d2);
    }
    // wave64 inclusive scan of packed counters
    u64 v = cnt;
    #pragma unroll
    for (int off=1; off<64; off<<=1){
      u64 t = __shfl_up(v, off, 64);
      if ((tid & 63) >= off) v += t;
    }
    if ((tid & 63) == 63) wsum[tid >> 6] = v;
    __syncthreads();
    u64 pre = 0, tot = 0;
    #pragma unroll
    for (int wv=0; wv<4; wv++){
      u64 wsv = wsum[wv];
      if (wv < (tid >> 6)) pre += wsv;
      tot += wsv;
    }
    u64 run = v + pre - cnt;   // packed exclusive counts
    u32 T0=(u32)(tot&0xFFFF), T1=(u32)((tot>>16)&0xFFFF), T2=(u32)((tot>>32)&0xFFFF);
    u64 Bp = ((u64)(T0) << 16) | ((u64)(T0+T1) << 32) | ((u64)(T0+T1+T2) << 48);
    #pragma unroll
    for (int k=0;k<16;k++){
      u32 d2 = (vpack >> (2*k)) & 3;
      u32 pos = (u32)((Bp >> (16*d2)) & 0xFFFF) + (u32)((run >> (16*d2)) & 0xFFFF);
      run += 1ull << (16*d2);
      keys[sw((int)pos)] = myk[k];
    }
    __syncthreads();
  }
  for (int k=0;k<16;k++){
    int j = k*256+tid;
    u32 d = (u32)((keys[sw(j)] >> shift) & (RBINS-1));
    bool headj = (j==0) || (((keys[sw(j-1)] >> shift) & (RBINS-1)) != d);
    if (headj) lstart[d] = (u32)j;
  }
  __syncthreads();
  for (int k=0;k<16;k++){
    int j = k*256+tid;
    u64 key = keys[sw(j)];
    if (key == ~0ull) continue;
    u32 d = (u32)((key >> shift) & (RBINS-1));
    u32 gpos = digitOff[d] + hist[(size_t)d*NTILES + blockIdx.x] + (u32)j - lstart[d];
    dst[gpos] = key;
  }
}

// streaming per-tile (head, crossHead) counts
__global__ __launch_bounds__(256) void k_tilesum(const u64* __restrict__ A, u64* __restrict__ tileSums){
  __shared__ u64 s[256];
  int tid = threadIdx.x;
  int start = blockIdx.x*TILE + tid*16;
  u64 prev = (start > 0 && start <= NE) ? A[start-1] : ~0ull;
  u32 th=0, tc=0;
  #pragma unroll
  for (int k=0;k<16;k++){
    int i = start + k;
    if (i < NE){
      u64 v = A[i];
      if ((v>>CODESHIFT) != (prev>>CODESHIFT)){
        th++;
        if ((v>>IDXBITS) & 1ull) tc++;
      }
      prev = v;
    }
  }
  s[tid] = ((u64)th<<32) | (u64)tc;
  __syncthreads();
  for (int off=128; off>0; off>>=1){
    if (tid<off) s[tid]+=s[tid+off];
    __syncthreads();
  }
  if (tid==0) tileSums[blockIdx.x] = s[0];
}

// exclusive scan over tiles; tileOff[NTILES] = grand total
__global__ void k_scan_tiles(u64* __restrict__ tileSums, u64* __restrict__ tileOff){
  __shared__ u64 s[256];
  int tid = threadIdx.x;
  u64 carry=0;
  for (int start=0; start<NTILES; start+=256){
    int idx=start+tid;
    u64 x = (idx<NTILES)? tileSums[idx] : 0;
    s[tid]=x; __syncthreads();
    for (int off=1;off<256;off<<=1){
      u64 t=(tid>=off)?s[tid-off]:0;
      __syncthreads();
      s[tid]+=t;
      __syncthreads();
    }
    u64 incl=s[tid], tot=s[255];
    if (idx<NTILES) tileOff[idx] = carry + incl - x;
    carry += tot;
    __syncthreads();
  }
  if (tid==0) tileOff[NTILES] = carry;
}

// streaming pass: crossing flags + staged pairs + dense codes[m]. NO gathers.
__global__ __launch_bounds__(256) void k_emit_light(const u64* __restrict__ A,
     const u64* __restrict__ tileOff, u64* __restrict__ pairs, u32* __restrict__ cursors,
     u64* __restrict__ codes, float* __restrict__ crossing_out){
  __shared__ u64 s[256];
  __shared__ u32 cnt[NBUCK], lcur[NBUCK];
  __shared__ u32 lofs[NBUCK+1];
  __shared__ u32 gbase[NBUCK];
  __shared__ u32 pscan[128];
  __shared__ u64 stage[STAGECAP];
  int tid=threadIdx.x, blk=blockIdx.x;
  int start = blk*TILE + tid*16;
  if (tid < NBUCK){ cnt[tid]=0; lcur[tid]=0; }
  u64 prev = (start > 0 && start <= NE) ? A[start-1] : ~0ull;
  u64 myk[16];
  u32 headm=0, crossm=0;
  #pragma unroll
  for (int k=0;k<16;k++){
    int i = start + k;
    u64 v = 0;
    if (i<NE){
      v = A[i];
      if ((v>>CODESHIFT) != (prev>>CODESHIFT)) headm |= 1u<<k;
      if ((v>>IDXBITS) & 1ull) crossm |= 1u<<k;
      prev = v;
    }
    myk[k]=v;
  }
  __syncthreads();
  #pragma unroll
  for (int k=0;k<16;k++){
    if ((start+k) < NE && ((crossm>>k)&1u))
      atomicAdd(&cnt[((u32)myk[k] & IDXMASK)>>BSHIFT], 1u);
  }
  u32 th = __popc(headm), tc = __popc(headm & crossm);
  u64 x = ((u64)th<<32)|(u64)tc;
  s[tid]=x; __syncthreads();
  for (int off=1;off<256;off<<=1){
    u64 t=(tid>=off)?s[tid-off]:0;
    __syncthreads();
    s[tid]+=t;
    __syncthreads();
  }
  u64 excl = s[tid]-x;
  if (tid < 128) pscan[tid] = (tid < NBUCK) ? cnt[tid] : 0;
  __syncthreads();
  for (int off=1; off<128; off<<=1){
    u32 t = 0;
    if (tid < 128 && tid >= off) t = pscan[tid-off];
    __syncthreads();
    if (tid < 128) pscan[tid] += t;
    __syncthreads();
  }
  if (tid < NBUCK) lofs[tid] = pscan[tid] - cnt[tid];
  if (tid == 0) lofs[NBUCK] = pscan[127];
  if (tid < NBUCK) gbase[tid] = atomicAdd(&cursors[tid], cnt[tid]);
  __syncthreads();
  bool use_stage = (lofs[NBUCK] <= STAGECAP);
  u64 baseOff = tileOff[blk] + excl;
  u32 H = (u32)(baseOff>>32);
  u32 C = (u32)(baseOff & 0xFFFFFFFFull);
  #pragma unroll
  for (int k=0;k<16;k++){
    int i = start+k;
    if (i>=NE) break;
    bool head  = (headm>>k)&1u;
    bool cross = (crossm>>k)&1u;
    if (head){ H++; if(cross) C++; }
    if (cross){
      int m = (int)C-1;
      u32 orig = (u32)myk[k] & IDXMASK;
      u32 b = orig>>BSHIFT;
      u32 r = atomicAdd(&lcur[b], 1u);
      u64 pr = ((u64)orig<<32) | (u64)(u32)m;
      if (use_stage) stage[lofs[b] + r] = pr;
      else           pairs[(size_t)b*BSZ + gbase[b] + r] = pr;
    }
    if (head){
      crossing_out[H-1] = cross ? 1.f : 0.f;
      if (cross) codes[C-1] = myk[k]>>CODESHIFT;
    }
  }
  __syncthreads();
  if (use_stage){
    int ncross = (int)lofs[NBUCK];
    for (int j = tid; j < ncross; j += 256){
      int lo=0, hi=NBUCK;
      while (hi - lo > 1){ int mid=(lo+hi)>>1; if ((int)lofs[mid] <= j) lo=mid; else hi=mid; }
      pairs[(size_t)lo*BSZ + gbase[lo] + (u32)(j - (int)lofs[lo])] = stage[j];
    }
  }
}

// gather-only verts pass; 40KB dummy LDS caps occupancy at 4 blocks/CU so psd stays L2-resident
__global__ __launch_bounds__(256) void k_verts(const u64* __restrict__ codes,
     const float4* __restrict__ psd, const u64* __restrict__ totptr, float* __restrict__ verts){
  __shared__ u64 dummy[5120];
  u32 ncross = (u32)(totptr[0] & 0xFFFFFFFFull);
  u32 stride = gridDim.x * blockDim.x;
  for (u32 i = blockIdx.x*blockDim.x + threadIdx.x; i < ncross; i += stride){
    u64 code = codes[i];
    u32 u0 = (u32)(code / NVERT), u1 = (u32)(code % NVERT);
    float4 a = psd[u0], b = psd[u1];
    float denom = a.w - b.w;
    float w0 = (-b.w)/denom, w1 = a.w/denom;
    verts[3*i+0] = a.x*w0 + b.x*w1;
    verts[3*i+1] = a.y*w0 + b.y*w1;
    verts[3*i+2] = a.z*w0 + b.z*w1;
  }
  if ((int)ncross < -1){ dummy[threadIdx.x] = codes[0]; verts[0] = (float)dummy[255]; }
}

__global__ void k_map_scatter(const u64* __restrict__ pairs, const u32* __restrict__ cursors,
                              float* __restrict__ mapF){
  int b = blockIdx.x / BPB, sub = blockIdx.x % BPB;
  u32 n = cursors[b];
  const u64* p = pairs + (size_t)b*BSZ;
  for (u32 i = (u32)(sub*256 + threadIdx.x); i < n; i += BPB*256){
    u64 v = p[i];
    mapF[(u32)(v>>32)] = (float)(int)(u32)v;
  }
}

__global__ void k_faces(const float* __restrict__ occF, float* faceRegion, float* __restrict__ numt){
  int t = blockIdx.x*blockDim.x + threadIdx.x;
  if (t>=NTET) return;
  int occ = (int)occF[t];
  int ntri = c_numtri[occ];
  float em[6];
  #pragma unroll
  for (int j=0;j<6;j++) em[j] = faceRegion[t*6+j];
  float f[6];
  #pragma unroll
  for (int j=0;j<6;j++){
    int tri = c_tritab[occ][j];
    f[j] = ((j/3) < ntri) ? em[tri] : -1.f;
  }
  #pragma unroll
  for (int j=0;j<6;j++) faceRegion[t*6+j] = f[j];
  numt[t] = (float)ntri;
}

extern "C" void kernel_launch(void* const* d_in, const int* in_sizes, int n_in,
                              void* d_out, int out_size, void* d_ws, size_t ws_size,
                              hipStream_t stream) {
  const float* pos = (const float*)d_in[0];
  const float* sdf = (const float*)d_in[1];
  const int*   tet = (const int*)d_in[2];
  float* out = (float*)d_out;

  // ws layout (hist aliases pairs region: disjoint lifetimes)
  char* w = (char*)d_ws;
  u64* bufA     = (u64*)w;                         // 57,600,000
  u32* digitTot = (u32*)(w + 57600000);            // 4096
  u32* digitOff = (u32*)(w + 57604096);            // 4096
  u64* tileSums = (u64*)(w + 57608192);            // 14,064
  u64* tileOff  = (u64*)(w + 57622256);            // 14,072 (NTILES+1)
  u32* cursors  = (u32*)(w + 57636328);            // 440 -> pad to 57636768
  float4* psd   = (float4*)(w + 57636768);         // 4,800,000
  u64* pairs_ws = (u64*)(w + 62436768);            // 57,600,000 -> ends 120,036,768
  u32* hist     = (u32*)pairs_ws;                  // 7,200,768 (sort-time only)

  u64* bufB  = (u64*)d_out;                        // sort pong buffer (bytes 0..57.6MB)
  u64* codes = (u64*)(out + CODES_ELEM);           // bytes 56MB..86.4MB (capacity 3.8M)

  k_pack<<<(NTET+255)/256, 256, 0, stream>>>(tet, sdf, bufA, out + NUMT_OFF);
  k_psd<<<(NVERT+255)/256, 256, 0, stream>>>(pos, sdf, psd);
  k_fillm1<<<(7200000/4 + 255)/256, 256, 0, stream>>>((float4*)(out + FACES_OFF), 7200000/4);

  u64 *src = bufA, *dst = bufB;
  for (int p=0; p<4; p++){
    int shift = SORT_BASE + RBITS*p;
    k_hist<<<NTILES, 256, 0, stream>>>(src, hist, shift);
    k_scan_digit<<<RBINS, 256, 0, stream>>>(hist, digitTot);
    k_scan_base<<<1, 1024, 0, stream>>>(digitTot, digitOff);
    k_scatter<<<NTILES, 256, 0, stream>>>(src, dst, hist, digitOff, shift);
    u64* tmp = src; src = dst; dst = tmp;
  }
  // sorted array in bufA

  k_tilesum<<<NTILES, 256, 0, stream>>>(bufA, tileSums);
  k_scan_tiles<<<1, 256, 0, stream>>>(tileSums, tileOff);

  hipMemsetAsync(out + CROSS_OFF, 0, (size_t)7200000*4, stream);
  hipMemsetAsync(cursors, 0, NBUCK*sizeof(u32), stream);

  k_emit_light<<<NTILES, 256, 0, stream>>>(bufA, tileOff, pairs_ws, cursors,
                                           codes, out + CROSS_OFF);

  hipMemsetAsync(out + VERTS_OFF, 0, (size_t)CODES_ELEM*4, stream);   // verts bytes 0..56MB
  k_verts<<<1024, 256, 0, stream>>>(codes, psd, tileOff + NTILES, out + VERTS_OFF);
  hipMemsetAsync(out + CODES_ELEM, 0, (size_t)(21600000-CODES_ELEM)*4, stream); // wipe codes -> zeros

  k_map_scatter<<<NBUCK*BPB, 256, 0, stream>>>(pairs_ws, cursors, out + FACES_OFF);
  k_faces<<<(NTET+255)/256, 256, 0, stream>>>(out + NUMT_OFF, out + FACES_OFF, out + NUMT_OFF);
}

// Round 10
// 843.768 us; speedup vs baseline: 1.1833x; 1.0262x over previous
//
#include <hip/hip_runtime.h>
#include <stdint.h>

typedef unsigned long long u64;
typedef unsigned int u32;

#define NVERT 300000
#define NTET  1200000
#define NE    (NTET*6)              // 7,200,000 edges
#define TILE  4096
#define NTILES ((NE + TILE - 1)/TILE)   // 1758
#define IDXBITS 23
#define IDXMASK ((1u<<IDXBITS)-1)
#define CODESHIFT 24                // key = code<<24 | cross<<23 | idx
#define RBITS 10
#define RBINS 1024
#define SORT_BASE 24
#define NPASS 4

// mapping-scatter buckets
#define BSHIFT 16
#define BSZ    65536
#define NBUCK  110
#define BPB    8
#define STAGECAP 2240

// output layout (float32 elements)
#define VERTS_OFF 0
#define FACES_OFF 21600000
#define NUMT_OFF  28800000
#define CROSS_OFF 30000000
#define CODES_ELEM 14000000         // codes at bytes 56MB..86.4MB of d_out

__constant__ int c_ea[6] = {0,0,0,1,1,2};
__constant__ int c_eb[6] = {1,2,3,2,3,3};
__constant__ int c_numtri[16] = {0,1,1,2,1,2,2,1,1,2,2,1,2,1,1,0};
__constant__ int c_tritab[16][6] = {
 {-1,-1,-1,-1,-1,-1},{1,0,2,-1,-1,-1},{4,0,3,-1,-1,-1},{1,4,2,1,3,4},
 {3,1,5,-1,-1,-1},{2,3,0,2,5,3},{1,4,0,1,5,4},{4,2,5,-1,-1,-1},
 {4,5,2,-1,-1,-1},{4,1,0,4,5,1},{3,2,0,3,5,2},{1,3,5,-1,-1,-1},
 {4,1,2,4,3,1},{3,0,4,-1,-1,-1},{2,0,1,-1,-1,-1},{-1,-1,-1,-1,-1,-1}};

__device__ __forceinline__ int sw(int j){ return j ^ ((j >> 4) & 15); }

// one thread per TET: 6 keys + occ nibble + fused GLOBAL histograms for all 4 passes
__global__ void k_pack(const int* __restrict__ tet, const float* __restrict__ sdf,
                       u64* __restrict__ dst, float* __restrict__ occF, u32* __restrict__ hist4g){
  __shared__ u32 h4[NPASS*RBINS];   // 16KB
  int tid = threadIdx.x;
  for (int r=tid; r<NPASS*RBINS; r+=256) h4[r]=0;
  __syncthreads();
  int t = blockIdx.x*blockDim.x + tid;
  if (t < NTET){
    int4 q = ((const int4*)tet)[t];
    int v[4] = {q.x, q.y, q.z, q.w};
    u32 o[4];
    int occ = 0;
    #pragma unroll
    for (int j=0;j<4;j++){ o[j] = sdf[v[j]] > 0.f ? 1u : 0u; occ |= (int)o[j] << j; }
    occF[t] = (float)occ;
    u64 base = (u64)t*6;
    #pragma unroll
    for (int k=0;k<6;k++){
      int a = v[c_ea[k]], b = v[c_eb[k]];
      u64 cross = (o[c_ea[k]] != o[c_eb[k]]) ? 1ull : 0ull;
      int e0 = min(a,b), e1 = max(a,b);
      u64 code = (u64)e0 * NVERT + (u64)e1;
      u64 key = (code << CODESHIFT) | (cross << IDXBITS) | (base + (u64)k);
      dst[base+k] = key;
      #pragma unroll
      for (int p=0;p<NPASS;p++)
        atomicAdd(&h4[p*RBINS + (u32)((key >> (SORT_BASE + RBITS*p)) & (RBINS-1))], 1u);
    }
  }
  __syncthreads();
  for (int r=tid; r<NPASS*RBINS; r+=256){
    u32 c = h4[r];
    if (c) atomicAdd(&hist4g[r], c);
  }
}

__global__ void k_psd(const float* __restrict__ pos, const float* __restrict__ sdf,
                      float4* __restrict__ psd){
  int v = blockIdx.x*blockDim.x + threadIdx.x;
  if (v < NVERT) psd[v] = make_float4(pos[3*v], pos[3*v+1], pos[3*v+2], sdf[v]);
}

__global__ void k_fillm1(float4* __restrict__ p, int n4){
  int i = blockIdx.x*blockDim.x + threadIdx.x;
  if (i < n4) p[i] = make_float4(-1.f,-1.f,-1.f,-1.f);
}

// exclusive scan of each pass's global histogram; grid = NPASS, block = 1024
__global__ __launch_bounds__(1024) void k_scan4(const u32* __restrict__ hist4g, u32* __restrict__ digitOff4){
  __shared__ u32 s[RBINS];
  int tid = threadIdx.x;
  const u32* src = hist4g + (size_t)blockIdx.x * RBINS;
  u32* dst = digitOff4 + (size_t)blockIdx.x * RBINS;
  u32 x = src[tid];
  s[tid]=x; __syncthreads();
  for (int off=1; off<RBINS; off<<=1){
    u32 t=(tid>=off)?s[tid-off]:0;
    __syncthreads();
    s[tid]+=t;
    __syncthreads();
  }
  dst[tid] = s[tid]-x;
}

// onesweep scatter: ticket-ordered tiles, in-kernel tile hist, decoupled lookback,
// 5 rounds of 2-bit stable LDS splits (wave64 shuffle scan)
__global__ __launch_bounds__(256) void k_scatter_os(const u64* __restrict__ src, u64* __restrict__ dst,
      const u32* __restrict__ digitOff, u32* __restrict__ pst, u32* __restrict__ ticket, int shift){
  __shared__ u64 keys[TILE];
  __shared__ u32 cnt[RBINS];
  __shared__ unsigned short lstart[RBINS];
  __shared__ u64 wsum[4];
  __shared__ int stile;
  int tid = threadIdx.x;
  if (tid==0) stile = (int)atomicAdd(ticket, 1u);
  for (int r=tid;r<RBINS;r+=256) cnt[r]=0;
  __syncthreads();
  int tile = stile;
  int base = tile * TILE;
  for (int k=0;k<16;k++){
    int j = k*256 + tid;
    int i = base + j;
    u64 key = (i < NE) ? src[i] : ~0ull;
    keys[sw(j)] = key;
    if (i < NE) atomicAdd(&cnt[(u32)((key >> shift) & (RBINS-1))], 1u);
  }
  __syncthreads();
  // publish PARTIAL counts early (unblocks successors)
  u32 oc[4];
  #pragma unroll
  for (int r=0;r<4;r++){
    int d = tid + r*256;
    oc[r] = cnt[d];
    atomicExch(&pst[(size_t)tile*RBINS + d], oc[r] | 0x40000000u);
  }
  // 5 rounds of 2-bit stable splits
  for (int q=0;q<RBITS;q+=2){
    int sh = shift + q;
    u64 myk[16];
    u32 vpack = 0;
    u64 c = 0;
    #pragma unroll
    for (int k=0;k<16;k++){
      myk[k] = keys[sw(tid*16+k)];
      u32 d2 = (u32)((myk[k] >> sh) & 3);
      vpack |= d2 << (2*k);
      c += 1ull << (16*d2);
    }
    u64 v = c;
    #pragma unroll
    for (int off=1; off<64; off<<=1){
      u64 t = __shfl_up(v, off, 64);
      if ((tid & 63) >= off) v += t;
    }
    if ((tid & 63) == 63) wsum[tid >> 6] = v;
    __syncthreads();
    u64 pre = 0, tot = 0;
    #pragma unroll
    for (int wv=0; wv<4; wv++){
      u64 wsv = wsum[wv];
      if (wv < (tid >> 6)) pre += wsv;
      tot += wsv;
    }
    u64 run = v + pre - c;
    u32 T0=(u32)(tot&0xFFFF), T1=(u32)((tot>>16)&0xFFFF), T2=(u32)((tot>>32)&0xFFFF);
    u64 Bp = ((u64)(T0) << 16) | ((u64)(T0+T1) << 32) | ((u64)(T0+T1+T2) << 48);
    #pragma unroll
    for (int k=0;k<16;k++){
      u32 d2 = (vpack >> (2*k)) & 3;
      u32 pos = (u32)((Bp >> (16*d2)) & 0xFFFF) + (u32)((run >> (16*d2)) & 0xFFFF);
      run += 1ull << (16*d2);
      keys[sw((int)pos)] = myk[k];
    }
    __syncthreads();
  }
  // local run starts
  for (int k=0;k<16;k++){
    int j = k*256+tid;
    u32 d = (u32)((keys[sw(j)] >> shift) & (RBINS-1));
    bool headj = (j==0) || (((keys[sw(j-1)] >> shift) & (RBINS-1)) != d);
    if (headj) lstart[d] = (unsigned short)j;
  }
  // lookback: exclusive tile base per digit (overwrites cnt), publish DONE inclusive
  #pragma unroll
  for (int r=0;r<4;r++){
    int d = tid + r*256;
    u32 sum = 0;
    int t2 = tile - 1;
    while (t2 >= 0){
      u32 v = atomicAdd(&pst[(size_t)t2*RBINS + d], 0u);
      if (!(v & 0xC0000000u)){ __builtin_amdgcn_s_sleep(1); continue; }
      sum += v & 0x0FFFFFFFu;
      if (v & 0x80000000u) break;
      t2--;
    }
    atomicExch(&pst[(size_t)tile*RBINS + d], (oc[r] + sum) | 0x80000000u);
    cnt[d] = sum;
  }
  __syncthreads();
  for (int k=0;k<16;k++){
    int j = k*256+tid;
    u64 key = keys[sw(j)];
    if (key == ~0ull) continue;
    u32 d = (u32)((key >> shift) & (RBINS-1));
    u32 gpos = digitOff[d] + cnt[d] + (u32)j - (u32)lstart[d];
    dst[gpos] = key;
  }
}

// streaming per-tile (head, crossHead) counts — vectorized loads
__global__ __launch_bounds__(256) void k_tilesum(const u64* __restrict__ A, u64* __restrict__ tileSums){
  __shared__ u64 s[256];
  int tid = threadIdx.x;
  int start = blockIdx.x*TILE + tid*16;
  u64 myk[16];
  if (start < NE){
    const ulonglong2* A2 = (const ulonglong2*)(A + start);
    #pragma unroll
    for (int k2=0;k2<8;k2++){ ulonglong2 t = A2[k2]; myk[2*k2]=t.x; myk[2*k2+1]=t.y; }
  } else {
    #pragma unroll
    for (int k=0;k<16;k++) myk[k]=0;
  }
  u64 prev = (start > 0 && start <= NE) ? A[start-1] : ~0ull;
  u32 th=0, tc=0;
  #pragma unroll
  for (int k=0;k<16;k++){
    int i = start + k;
    if (i < NE){
      u64 v = myk[k];
      if ((v>>CODESHIFT) != (prev>>CODESHIFT)){
        th++;
        if ((v>>IDXBITS) & 1ull) tc++;
      }
      prev = v;
    }
  }
  s[tid] = ((u64)th<<32) | (u64)tc;
  __syncthreads();
  for (int off=128; off>0; off>>=1){
    if (tid<off) s[tid]+=s[tid+off];
    __syncthreads();
  }
  if (tid==0) tileSums[blockIdx.x] = s[0];
}

// exclusive scan over tiles; tileOff[NTILES] = grand total
__global__ void k_scan_tiles(u64* __restrict__ tileSums, u64* __restrict__ tileOff){
  __shared__ u64 s[256];
  int tid = threadIdx.x;
  u64 carry=0;
  for (int start=0; start<NTILES; start+=256){
    int idx=start+tid;
    u64 x = (idx<NTILES)? tileSums[idx] : 0;
    s[tid]=x; __syncthreads();
    for (int off=1;off<256;off<<=1){
      u64 t=(tid>=off)?s[tid-off]:0;
      __syncthreads();
      s[tid]+=t;
      __syncthreads();
    }
    u64 incl=s[tid], tot=s[255];
    if (idx<NTILES) tileOff[idx] = carry + incl - x;
    carry += tot;
    __syncthreads();
  }
  if (tid==0) tileOff[NTILES] = carry;
}

// streaming pass: crossing flags + staged pairs + dense codes[m]. NO gathers. Vectorized loads.
__global__ __launch_bounds__(256) void k_emit_light(const u64* __restrict__ A,
     const u64* __restrict__ tileOff, u64* __restrict__ pairs, u32* __restrict__ cursors,
     u64* __restrict__ codes, float* __restrict__ crossing_out){
  __shared__ u64 s[256];
  __shared__ u32 cnt[NBUCK], lcur[NBUCK];
  __shared__ u32 lofs[NBUCK+1];
  __shared__ u32 gbase[NBUCK];
  __shared__ u32 pscan[128];
  __shared__ u64 stage[STAGECAP];
  int tid=threadIdx.x, blk=blockIdx.x;
  int start = blk*TILE + tid*16;
  if (tid < NBUCK){ cnt[tid]=0; lcur[tid]=0; }
  u64 myk[16];
  if (start < NE){
    const ulonglong2* A2 = (const ulonglong2*)(A + start);
    #pragma unroll
    for (int k2=0;k2<8;k2++){ ulonglong2 t = A2[k2]; myk[2*k2]=t.x; myk[2*k2+1]=t.y; }
  } else {
    #pragma unroll
    for (int k=0;k<16;k++) myk[k]=0;
  }
  u64 prev = (start > 0 && start <= NE) ? A[start-1] : ~0ull;
  u32 headm=0, crossm=0;
  #pragma unroll
  for (int k=0;k<16;k++){
    int i = start + k;
    if (i<NE){
      u64 v = myk[k];
      if ((v>>CODESHIFT) != (prev>>CODESHIFT)) headm |= 1u<<k;
      if ((v>>IDXBITS) & 1ull) crossm |= 1u<<k;
      prev = v;
    }
  }
  __syncthreads();
  #pragma unroll
  for (int k=0;k<16;k++){
    if ((start+k) < NE && ((crossm>>k)&1u))
      atomicAdd(&cnt[((u32)myk[k] & IDXMASK)>>BSHIFT], 1u);
  }
  u32 th = __popc(headm), tc = __popc(headm & crossm);
  u64 x = ((u64)th<<32)|(u64)tc;
  s[tid]=x; __syncthreads();
  for (int off=1;off<256;off<<=1){
    u64 t=(tid>=off)?s[tid-off]:0;
    __syncthreads();
    s[tid]+=t;
    __syncthreads();
  }
  u64 excl = s[tid]-x;
  if (tid < 128) pscan[tid] = (tid < NBUCK) ? cnt[tid] : 0;
  __syncthreads();
  for (int off=1; off<128; off<<=1){
    u32 t = 0;
    if (tid < 128 && tid >= off) t = pscan[tid-off];
    __syncthreads();
    if (tid < 128) pscan[tid] += t;
    __syncthreads();
  }
  if (tid < NBUCK) lofs[tid] = pscan[tid] - cnt[tid];
  if (tid == 0) lofs[NBUCK] = pscan[127];
  if (tid < NBUCK) gbase[tid] = atomicAdd(&cursors[tid], cnt[tid]);
  __syncthreads();
  bool use_stage = (lofs[NBUCK] <= STAGECAP);
  u64 baseOff = tileOff[blk] + excl;
  u32 H = (u32)(baseOff>>32);
  u32 C = (u32)(baseOff & 0xFFFFFFFFull);
  #pragma unroll
  for (int k=0;k<16;k++){
    int i = start+k;
    if (i>=NE) break;
    bool head  = (headm>>k)&1u;
    bool cross = (crossm>>k)&1u;
    if (head){ H++; if(cross) C++; }
    if (cross){
      int m = (int)C-1;
      u32 orig = (u32)myk[k] & IDXMASK;
      u32 b = orig>>BSHIFT;
      u32 r = atomicAdd(&lcur[b], 1u);
      u64 pr = ((u64)orig<<32) | (u64)(u32)m;
      if (use_stage) stage[lofs[b] + r] = pr;
      else           pairs[(size_t)b*BSZ + gbase[b] + r] = pr;
    }
    if (head){
      crossing_out[H-1] = cross ? 1.f : 0.f;
      if (cross) codes[C-1] = myk[k]>>CODESHIFT;
    }
  }
  __syncthreads();
  if (use_stage){
    int ncross = (int)lofs[NBUCK];
    for (int j = tid; j < ncross; j += 256){
      int lo=0, hi=NBUCK;
      while (hi - lo > 1){ int mid=(lo+hi)>>1; if ((int)lofs[mid] <= j) lo=mid; else hi=mid; }
      pairs[(size_t)lo*BSZ + gbase[lo] + (u32)(j - (int)lofs[lo])] = stage[j];
    }
  }
}

// gather-only verts pass; 40KB dummy LDS caps occupancy so psd stays L2-resident
__global__ __launch_bounds__(256) void k_verts(const u64* __restrict__ codes,
     const float4* __restrict__ psd, const u64* __restrict__ totptr, float* __restrict__ verts){
  __shared__ u64 dummy[5120];
  u32 ncross = (u32)(totptr[0] & 0xFFFFFFFFull);
  u32 stride = gridDim.x * blockDim.x;
  for (u32 i = blockIdx.x*blockDim.x + threadIdx.x; i < ncross; i += stride){
    u64 code = codes[i];
    u32 u0 = (u32)(code / NVERT), u1 = (u32)(code % NVERT);
    float4 a = psd[u0], b = psd[u1];
    float denom = a.w - b.w;
    float w0 = (-b.w)/denom, w1 = a.w/denom;
    verts[3*i+0] = a.x*w0 + b.x*w1;
    verts[3*i+1] = a.y*w0 + b.y*w1;
    verts[3*i+2] = a.z*w0 + b.z*w1;
  }
  if ((int)ncross < -1){ dummy[threadIdx.x] = codes[0]; verts[0] = (float)dummy[255]; }
}

__global__ void k_map_scatter(const u64* __restrict__ pairs, const u32* __restrict__ cursors,
                              float* __restrict__ mapF){
  int b = blockIdx.x / BPB, sub = blockIdx.x % BPB;
  u32 n = cursors[b];
  const u64* p = pairs + (size_t)b*BSZ;
  for (u32 i = (u32)(sub*256 + threadIdx.x); i < n; i += BPB*256){
    u64 v = p[i];
    mapF[(u32)(v>>32)] = (float)(int)(u32)v;
  }
}

__global__ void k_faces(const float* __restrict__ occF, float* faceRegion, float* __restrict__ numt){
  int t = blockIdx.x*blockDim.x + threadIdx.x;
  if (t>=NTET) return;
  int occ = (int)occF[t];
  int ntri = c_numtri[occ];
  float em[6];
  #pragma unroll
  for (int j=0;j<6;j++) em[j] = faceRegion[t*6+j];
  float f[6];
  #pragma unroll
  for (int j=0;j<6;j++){
    int tri = c_tritab[occ][j];
    f[j] = ((j/3) < ntri) ? em[tri] : -1.f;
  }
  #pragma unroll
  for (int j=0;j<6;j++) faceRegion[t*6+j] = f[j];
  numt[t] = (float)ntri;
}

extern "C" void kernel_launch(void* const* d_in, const int* in_sizes, int n_in,
                              void* d_out, int out_size, void* d_ws, size_t ws_size,
                              hipStream_t stream) {
  const float* pos = (const float*)d_in[0];
  const float* sdf = (const float*)d_in[1];
  const int*   tet = (const int*)d_in[2];
  float* out = (float*)d_out;

  // ws layout
  char* w = (char*)d_ws;
  u64* bufA      = (u64*)w;                        // 57,600,000
  u32* hist4g    = (u32*)(w + 57600000);           // 16,384
  u32* digitOff4 = (u32*)(w + 57616384);           // 16,384
  u64* tileSums  = (u64*)(w + 57632768);           // 14,064
  u64* tileOff   = (u64*)(w + 57646832);           // 14,072 (NTILES+1)
  u32* cursors   = (u32*)(w + 57660904);           // 440
  u32* tickets   = (u32*)(w + 57661344);           // 16 -> pad to 57661952
  float4* psd    = (float4*)(w + 57661952);        // 4,800,000
  u32* pst       = (u32*)(w + 62461952);           // 4*1758*1024*4 = 28,835,840 (sort-time)
  u64* pairs_ws  = (u64*)(w + 62461952);           // 57,600,000 (emit-time, aliases pst) -> ends 120,061,952

  u64* bufB  = (u64*)d_out;                        // sort pong buffer (bytes 0..57.6MB)
  u64* codes = (u64*)(out + CODES_ELEM);           // bytes 56MB..86.4MB

  hipMemsetAsync(hist4g, 0, NPASS*RBINS*sizeof(u32), stream);
  hipMemsetAsync(tickets, 0, NPASS*sizeof(u32), stream);
  hipMemsetAsync(pst, 0, (size_t)NPASS*NTILES*RBINS*sizeof(u32), stream);

  k_pack<<<(NTET+255)/256, 256, 0, stream>>>(tet, sdf, bufA, out + NUMT_OFF, hist4g);
  k_psd<<<(NVERT+255)/256, 256, 0, stream>>>(pos, sdf, psd);
  k_fillm1<<<(7200000/4 + 255)/256, 256, 0, stream>>>((float4*)(out + FACES_OFF), 7200000/4);

  k_scan4<<<NPASS, 1024, 0, stream>>>(hist4g, digitOff4);

  u64 *src = bufA, *dst = bufB;
  for (int p=0; p<NPASS; p++){
    int shift = SORT_BASE + RBITS*p;
    k_scatter_os<<<NTILES, 256, 0, stream>>>(src, dst,
        digitOff4 + (size_t)p*RBINS, pst + (size_t)p*NTILES*RBINS, tickets + p, shift);
    u64* tmp = src; src = dst; dst = tmp;
  }
  // 4 passes: bufA->bufB->bufA->bufB->bufA — sorted array in bufA (ws)

  k_tilesum<<<NTILES, 256, 0, stream>>>(bufA, tileSums);
  k_scan_tiles<<<1, 256, 0, stream>>>(tileSums, tileOff);

  hipMemsetAsync(out + CROSS_OFF, 0, (size_t)7200000*4, stream);
  hipMemsetAsync(cursors, 0, NBUCK*sizeof(u32), stream);

  k_emit_light<<<NTILES, 256, 0, stream>>>(bufA, tileOff, pairs_ws, cursors,
                                           codes, out + CROSS_OFF);

  hipMemsetAsync(out + VERTS_OFF, 0, (size_t)CODES_ELEM*4, stream);   // verts bytes 0..56MB
  k_verts<<<1024, 256, 0, stream>>>(codes, psd, tileOff + NTILES, out + VERTS_OFF);
  hipMemsetAsync(out + CODES_ELEM, 0, (size_t)(21600000-CODES_ELEM)*4, stream); // wipe codes

  k_map_scatter<<<NBUCK*BPB, 256, 0, stream>>>(pairs_ws, cursors, out + FACES_OFF);
  k_faces<<<(NTET+255)/256, 256, 0, stream>>>(out + NUMT_OFF, out + FACES_OFF, out + NUMT_OFF);
}